// Round 1
// baseline (855.460 us; speedup 1.0000x reference)
//
#include <hip/hip_runtime.h>
#include <hip/hip_bf16.h>

#define N_NODES_C 50000
#define N_EDGES_C 800000
#define N_GRAPHS_C 64

// ---------------------------------------------------------------- degrees
__global__ void k_deg(const int* __restrict__ src, const int* __restrict__ dst,
                      float* __restrict__ degO, float* __restrict__ degI, int nE) {
    int e = blockIdx.x * blockDim.x + threadIdx.x;
    if (e < nE) {
        unsafeAtomicAdd(&degO[src[e]], 1.0f);
        unsafeAtomicAdd(&degI[dst[e]], 1.0f);
    }
}

// deg -> rsqrt(clip(deg,1)) in place
__global__ void k_rs(float* __restrict__ degO, float* __restrict__ degI, int nV) {
    int v = blockIdx.x * blockDim.x + threadIdx.x;
    if (v < nV) {
        degO[v] = rsqrtf(fmaxf(degO[v], 1.0f));
        degI[v] = rsqrtf(fmaxf(degI[v], 1.0f));
    }
}

// ------------------------------------------------- layer-1 scatter (128 wide)
// one wave (64 lanes) per edge, float2 per lane: agg1[dst] += x[src]*rsO[src]
__global__ void k_scatter1(const float* __restrict__ x, const int* __restrict__ src,
                           const int* __restrict__ dst, const float* __restrict__ rsO,
                           float* __restrict__ agg1, int nE) {
    long long t = (long long)blockIdx.x * blockDim.x + threadIdx.x;
    int e = (int)(t >> 6);
    int lane = (int)(t & 63);
    if (e >= nE) return;
    int s = src[e], d = dst[e];
    float w = rsO[s];
    float2 v = ((const float2*)(x + (size_t)s * 128))[lane];
    float* out = agg1 + (size_t)d * 128 + lane * 2;
    unsafeAtomicAdd(out,     v.x * w);
    unsafeAtomicAdd(out + 1, v.y * w);
}

// ------------------------------------- fused node GEMMs: h1 = relu((agg1*rsI)@W1+b1)
//                                       y = (h1*rsO)@W2     (b2 folded into pooling)
__global__ __launch_bounds__(256, 2) void k_gemm(
    const float* __restrict__ agg1, const float* __restrict__ rsI,
    const float* __restrict__ rsO, const float* __restrict__ W1,
    const float* __restrict__ b1, const float* __restrict__ W2,
    float* __restrict__ y, int nV)
{
    __shared__ float Wl[128 * 128];   // 64 KB
    __shared__ float Al[32 * 128];    // 16 KB (A tile, then h1 tile)
    const int tid = threadIdx.x;
    const int row0 = blockIdx.x * 32;

    // stage W1 (16384 floats, float4 x 16 per thread)
    for (int i = tid * 4; i < 16384; i += 1024)
        *(float4*)&Wl[i] = *(const float4*)&W1[i];
    // stage scaled A tile
    for (int i = tid * 4; i < 4096; i += 1024) {
        int r = i >> 7, c = i & 127;
        int row = row0 + r;
        float4 v = make_float4(0.f, 0.f, 0.f, 0.f);
        if (row < nV) {
            v = *(const float4*)&agg1[(size_t)row * 128 + c];
            float s = rsI[row];
            v.x *= s; v.y *= s; v.z *= s; v.w *= s;
        }
        *(float4*)&Al[i] = v;
    }
    __syncthreads();

    const int fg = tid & 15;   // feature group: cols fg*8 .. fg*8+7
    const int rg = tid >> 4;   // row group: rows rg*2, rg*2+1
    const int r0 = rg * 2;
    float acc[2][8];
#pragma unroll
    for (int r = 0; r < 2; ++r)
#pragma unroll
        for (int j = 0; j < 8; ++j) acc[r][j] = 0.f;

#pragma unroll 4
    for (int k = 0; k < 128; ++k) {
        float a0 = Al[r0 * 128 + k];
        float a1 = Al[(r0 + 1) * 128 + k];
        const float* wp = &Wl[k * 128 + fg * 8];
        float4 w0 = *(const float4*)wp;
        float4 w1 = *(const float4*)(wp + 4);
        acc[0][0] += a0 * w0.x; acc[0][1] += a0 * w0.y;
        acc[0][2] += a0 * w0.z; acc[0][3] += a0 * w0.w;
        acc[0][4] += a0 * w1.x; acc[0][5] += a0 * w1.y;
        acc[0][6] += a0 * w1.z; acc[0][7] += a0 * w1.w;
        acc[1][0] += a1 * w0.x; acc[1][1] += a1 * w0.y;
        acc[1][2] += a1 * w0.z; acc[1][3] += a1 * w0.w;
        acc[1][4] += a1 * w1.x; acc[1][5] += a1 * w1.y;
        acc[1][6] += a1 * w1.z; acc[1][7] += a1 * w1.w;
    }
    __syncthreads();
    // bias + relu, write h1 back into Al
#pragma unroll
    for (int r = 0; r < 2; ++r)
#pragma unroll
        for (int j = 0; j < 8; ++j) {
            float h = acc[r][j] + b1[fg * 8 + j];
            Al[(r0 + r) * 128 + fg * 8 + j] = fmaxf(h, 0.f);
        }
    __syncthreads();

    // layer-2 GEMM: 16 outputs, rsO folded (scalar per row, applied post-sum)
    const int of = tid & 15;
    const int rr = tid >> 4;   // rows rr, rr+16
    float s0 = 0.f, s1 = 0.f;
#pragma unroll 4
    for (int k = 0; k < 128; ++k) {
        float w = W2[k * 16 + of];
        s0 += Al[rr * 128 + k] * w;
        s1 += Al[(rr + 16) * 128 + k] * w;
    }
    int rowA = row0 + rr, rowB = row0 + rr + 16;
    if (rowA < nV) y[(size_t)rowA * 16 + of] = s0 * rsO[rowA];
    if (rowB < nV) y[(size_t)rowB * 16 + of] = s1 * rsO[rowB];
}

// ------------------------------------------------- layer-2 scatter (16 wide)
__global__ void k_scatter2(const float* __restrict__ y, const int* __restrict__ src,
                           const int* __restrict__ dst, float* __restrict__ agg2, int nE) {
    long long t = (long long)blockIdx.x * blockDim.x + threadIdx.x;
    int e = (int)(t >> 4);
    int f = (int)(t & 15);
    if (e >= nE) return;
    unsafeAtomicAdd(&agg2[(size_t)dst[e] * 16 + f], y[(size_t)src[e] * 16 + f]);
}

// ------------------------------------------------- per-graph mean pool (+b2)
__device__ __forceinline__ int lowerb(const int* __restrict__ a, int n, int key) {
    int lo = 0, hi = n;
    while (lo < hi) { int m = (lo + hi) >> 1; if (a[m] < key) lo = m + 1; else hi = m; }
    return lo;
}

__global__ __launch_bounds__(256) void k_pool(
    const float* __restrict__ agg2, const float* __restrict__ rsI,
    const int* __restrict__ gid, const float* __restrict__ b2,
    float* __restrict__ out, int nV)
{
    __shared__ float red[256][16];   // 16 KB
    const int g = blockIdx.x;
    const int tid = threadIdx.x;
    const int lo = lowerb(gid, nV, g);
    const int hi = lowerb(gid, nV, g + 1);

    float acc[16];
#pragma unroll
    for (int f = 0; f < 16; ++f) acc[f] = 0.f;

    for (int v = lo + tid; v < hi; v += 256) {
        float w = rsI[v];
        const float4* p = (const float4*)(agg2 + (size_t)v * 16);
        float4 a = p[0], b = p[1], c = p[2], d = p[3];
        acc[0] += a.x * w; acc[1] += a.y * w; acc[2]  += a.z * w; acc[3]  += a.w * w;
        acc[4] += b.x * w; acc[5] += b.y * w; acc[6]  += b.z * w; acc[7]  += b.w * w;
        acc[8] += c.x * w; acc[9] += c.y * w; acc[10] += c.z * w; acc[11] += c.w * w;
        acc[12] += d.x * w; acc[13] += d.y * w; acc[14] += d.z * w; acc[15] += d.w * w;
    }
#pragma unroll
    for (int f = 0; f < 16; ++f) red[tid][f] = acc[f];
    __syncthreads();
    for (int s = 128; s > 0; s >>= 1) {
        if (tid < s)
#pragma unroll
            for (int f = 0; f < 16; ++f) red[tid][f] += red[tid + s][f];
        __syncthreads();
    }
    if (tid < 16) {
        int n = hi - lo;
        out[g * 16 + tid] = (n > 0) ? (red[0][tid] / (float)n + b2[tid]) : 0.f;
    }
}

// ----------------------------------------------------------------- launch
extern "C" void kernel_launch(void* const* d_in, const int* in_sizes, int n_in,
                              void* d_out, int out_size, void* d_ws, size_t ws_size,
                              hipStream_t stream) {
    const float* x   = (const float*)d_in[0];
    const float* W1  = (const float*)d_in[1];
    const float* b1  = (const float*)d_in[2];
    const float* W2  = (const float*)d_in[3];
    const float* b2  = (const float*)d_in[4];
    const int*   src = (const int*)d_in[5];
    const int*   dst = (const int*)d_in[6];
    const int*   gid = (const int*)d_in[7];
    float* out = (float*)d_out;

    float* ws   = (float*)d_ws;
    float* rsO  = ws;                 //    50,000
    float* rsI  = ws + 50000;         //    50,000
    float* agg1 = ws + 100000;        // 6,400,000
    float* agg2 = ws + 6500000;       //   800,000
    float* y    = ws + 7300000;       //   800,000 (not zeroed: fully written)

    // zero rsO|rsI|agg1|agg2 in one contiguous memset (29.2 MB)
    hipMemsetAsync(d_ws, 0, (size_t)7300000 * sizeof(float), stream);

    k_deg<<<(N_EDGES_C + 255) / 256, 256, 0, stream>>>(src, dst, rsO, rsI, N_EDGES_C);
    k_rs<<<(N_NODES_C + 255) / 256, 256, 0, stream>>>(rsO, rsI, N_NODES_C);
    k_scatter1<<<N_EDGES_C / 4, 256, 0, stream>>>(x, src, dst, rsO, agg1, N_EDGES_C);
    k_gemm<<<(N_NODES_C + 31) / 32, 256, 0, stream>>>(agg1, rsI, rsO, W1, b1, W2, y, N_NODES_C);
    k_scatter2<<<N_EDGES_C / 16, 256, 0, stream>>>(y, src, dst, agg2, N_EDGES_C);
    k_pool<<<N_GRAPHS_C, 256, 0, stream>>>(agg2, rsI, gid, b2, out, N_NODES_C);
}

// Round 2
// 433.457 us; speedup vs baseline: 1.9736x; 1.9736x over previous
//
#include <hip/hip_runtime.h>
#include <hip/hip_bf16.h>

#define N_NODES_C 50000
#define N_EDGES_C 800000
#define N_GRAPHS_C 64

// ---------------------------------------------------------------- counts
__global__ void k_count(const int* __restrict__ src, const int* __restrict__ dst,
                        int* __restrict__ cntO, int* __restrict__ cntI, int nE) {
    int e = blockIdx.x * blockDim.x + threadIdx.x;
    if (e < nE) {
        atomicAdd(&cntO[src[e]], 1);
        atomicAdd(&cntI[dst[e]], 1);
    }
}

// counts -> rsqrt(clip(deg,1))
__global__ void k_rs(const int* __restrict__ cntO, const int* __restrict__ cntI,
                     float* __restrict__ rsO, float* __restrict__ rsI, int nV) {
    int v = blockIdx.x * blockDim.x + threadIdx.x;
    if (v < nV) {
        rsO[v] = rsqrtf((float)max(cntO[v], 1));
        rsI[v] = rsqrtf((float)max(cntI[v], 1));
    }
}

// ------------------------------------------- single-block exclusive scan (50k)
__global__ __launch_bounds__(1024) void k_scan(const int* __restrict__ cntI,
                                               int* __restrict__ rowptr,
                                               int* __restrict__ cursor, int nV) {
    __shared__ int part[1024];
    const int tid = threadIdx.x;
    const int CH = (nV + 1023) / 1024;
    const int base = tid * CH;
    int s = 0;
    for (int i = 0; i < CH; ++i) {
        int idx = base + i;
        if (idx < nV) s += cntI[idx];
    }
    part[tid] = s;
    __syncthreads();
    for (int off = 1; off < 1024; off <<= 1) {
        int t = (tid >= off) ? part[tid - off] : 0;
        __syncthreads();
        part[tid] += t;
        __syncthreads();
    }
    int run = part[tid] - s;   // exclusive offset for this chunk
    for (int i = 0; i < CH; ++i) {
        int idx = base + i;
        if (idx < nV) {
            int c = cntI[idx];
            rowptr[idx] = run;
            cursor[idx] = run;
            run += c;
        }
    }
    if (tid == 1023) rowptr[nV] = part[1023];
}

// ------------------------------------------------------------------- CSR fill
__global__ void k_fill(const int* __restrict__ src, const int* __restrict__ dst,
                       int* __restrict__ cursor, int* __restrict__ csr_src, int nE) {
    int e = blockIdx.x * blockDim.x + threadIdx.x;
    if (e < nE) {
        int p = atomicAdd(&cursor[dst[e]], 1);
        csr_src[p] = src[e];
    }
}

// ------------------------------------- layer-1 aggregation: gather-sum per dst
// one wave per node, float2 per lane; agg1[v] = rsI[v] * sum_in x[s]*rsO[s]
__global__ __launch_bounds__(256) void k_agg1(
    const float* __restrict__ x, const int* __restrict__ rowptr,
    const int* __restrict__ csr_src, const float* __restrict__ rsO,
    const float* __restrict__ rsI, float* __restrict__ agg1, int nV)
{
    long long t = (long long)blockIdx.x * blockDim.x + threadIdx.x;
    int v = (int)(t >> 6);
    int lane = (int)(t & 63);
    if (v >= nV) return;
    int beg = rowptr[v], end = rowptr[v + 1];
    float2 acc = make_float2(0.f, 0.f);
    if (beg < end) {
        int s = csr_src[beg];
        for (int j = beg; j < end; ) {
            int sn = (j + 1 < end) ? csr_src[j + 1] : 0;   // prefetch next index
            float w = rsO[s];
            float2 xv = ((const float2*)(x + (size_t)s * 128))[lane];
            acc.x += xv.x * w;
            acc.y += xv.y * w;
            ++j; s = sn;
        }
    }
    float ri = rsI[v];
    ((float2*)(agg1 + (size_t)v * 128))[lane] = make_float2(acc.x * ri, acc.y * ri);
}

// ------------------------------------- fused node GEMMs: h1 = relu(agg1@W1+b1)
//                                       y = (h1*rsO)@W2     (b2 folded into pooling)
__global__ __launch_bounds__(256, 2) void k_gemm(
    const float* __restrict__ agg1, const float* __restrict__ rsO,
    const float* __restrict__ W1, const float* __restrict__ b1,
    const float* __restrict__ W2, float* __restrict__ y, int nV)
{
    __shared__ float Wl[128 * 128];   // 64 KB
    __shared__ float Al[32 * 128];    // 16 KB (A tile, then h1 tile)
    const int tid = threadIdx.x;
    const int row0 = blockIdx.x * 32;

    for (int i = tid * 4; i < 16384; i += 1024)
        *(float4*)&Wl[i] = *(const float4*)&W1[i];
    for (int i = tid * 4; i < 4096; i += 1024) {
        int r = i >> 7, c = i & 127;
        int row = row0 + r;
        float4 v = make_float4(0.f, 0.f, 0.f, 0.f);
        if (row < nV) v = *(const float4*)&agg1[(size_t)row * 128 + c];
        *(float4*)&Al[i] = v;
    }
    __syncthreads();

    const int fg = tid & 15;
    const int rg = tid >> 4;
    const int r0 = rg * 2;
    float acc[2][8];
#pragma unroll
    for (int r = 0; r < 2; ++r)
#pragma unroll
        for (int j = 0; j < 8; ++j) acc[r][j] = 0.f;

#pragma unroll 4
    for (int k = 0; k < 128; ++k) {
        float a0 = Al[r0 * 128 + k];
        float a1 = Al[(r0 + 1) * 128 + k];
        const float* wp = &Wl[k * 128 + fg * 8];
        float4 w0 = *(const float4*)wp;
        float4 w1 = *(const float4*)(wp + 4);
        acc[0][0] += a0 * w0.x; acc[0][1] += a0 * w0.y;
        acc[0][2] += a0 * w0.z; acc[0][3] += a0 * w0.w;
        acc[0][4] += a0 * w1.x; acc[0][5] += a0 * w1.y;
        acc[0][6] += a0 * w1.z; acc[0][7] += a0 * w1.w;
        acc[1][0] += a1 * w0.x; acc[1][1] += a1 * w0.y;
        acc[1][2] += a1 * w0.z; acc[1][3] += a1 * w0.w;
        acc[1][4] += a1 * w1.x; acc[1][5] += a1 * w1.y;
        acc[1][6] += a1 * w1.z; acc[1][7] += a1 * w1.w;
    }
    __syncthreads();
#pragma unroll
    for (int r = 0; r < 2; ++r)
#pragma unroll
        for (int j = 0; j < 8; ++j) {
            float h = acc[r][j] + b1[fg * 8 + j];
            Al[(r0 + r) * 128 + fg * 8 + j] = fmaxf(h, 0.f);
        }
    __syncthreads();

    const int of = tid & 15;
    const int rr = tid >> 4;
    float s0 = 0.f, s1 = 0.f;
#pragma unroll 4
    for (int k = 0; k < 128; ++k) {
        float w = W2[k * 16 + of];
        s0 += Al[rr * 128 + k] * w;
        s1 += Al[(rr + 16) * 128 + k] * w;
    }
    int rowA = row0 + rr, rowB = row0 + rr + 16;
    if (rowA < nV) y[(size_t)rowA * 16 + of] = s0 * rsO[rowA];
    if (rowB < nV) y[(size_t)rowB * 16 + of] = s1 * rsO[rowB];
}

// ------------------------------------- layer-2 aggregation: gather-sum per dst
// one wave per node: 4 edge-groups x 16 features, shfl reduce across groups
__global__ __launch_bounds__(256) void k_agg2(
    const float* __restrict__ y, const int* __restrict__ rowptr,
    const int* __restrict__ csr_src, float* __restrict__ agg2, int nV)
{
    long long t = (long long)blockIdx.x * blockDim.x + threadIdx.x;
    int v = (int)(t >> 6);
    int lane = (int)(t & 63);
    if (v >= nV) return;
    int f = lane & 15, g = lane >> 4;
    int beg = rowptr[v], end = rowptr[v + 1];
    float acc = 0.f;
    for (int j = beg + g; j < end; j += 4) {
        int s = csr_src[j];
        acc += y[(size_t)s * 16 + f];
    }
    acc += __shfl_xor(acc, 16, 64);
    acc += __shfl_xor(acc, 32, 64);
    if (g == 0) agg2[(size_t)v * 16 + f] = acc;
}

// ------------------------------------------------- per-graph mean pool (+b2)
__device__ __forceinline__ int lowerb(const int* __restrict__ a, int n, int key) {
    int lo = 0, hi = n;
    while (lo < hi) { int m = (lo + hi) >> 1; if (a[m] < key) lo = m + 1; else hi = m; }
    return lo;
}

__global__ __launch_bounds__(256) void k_pool(
    const float* __restrict__ agg2, const float* __restrict__ rsI,
    const int* __restrict__ gid, const float* __restrict__ b2,
    float* __restrict__ out, int nV)
{
    __shared__ float red[256][16];
    const int g = blockIdx.x;
    const int tid = threadIdx.x;
    const int lo = lowerb(gid, nV, g);
    const int hi = lowerb(gid, nV, g + 1);

    float acc[16];
#pragma unroll
    for (int f = 0; f < 16; ++f) acc[f] = 0.f;

    for (int v = lo + tid; v < hi; v += 256) {
        float w = rsI[v];
        const float4* p = (const float4*)(agg2 + (size_t)v * 16);
        float4 a = p[0], b = p[1], c = p[2], d = p[3];
        acc[0] += a.x * w; acc[1] += a.y * w; acc[2]  += a.z * w; acc[3]  += a.w * w;
        acc[4] += b.x * w; acc[5] += b.y * w; acc[6]  += b.z * w; acc[7]  += b.w * w;
        acc[8] += c.x * w; acc[9] += c.y * w; acc[10] += c.z * w; acc[11] += c.w * w;
        acc[12] += d.x * w; acc[13] += d.y * w; acc[14] += d.z * w; acc[15] += d.w * w;
    }
#pragma unroll
    for (int f = 0; f < 16; ++f) red[tid][f] = acc[f];
    __syncthreads();
    for (int s = 128; s > 0; s >>= 1) {
        if (tid < s)
#pragma unroll
            for (int f = 0; f < 16; ++f) red[tid][f] += red[tid + s][f];
        __syncthreads();
    }
    if (tid < 16) {
        int n = hi - lo;
        out[g * 16 + tid] = (n > 0) ? (red[0][tid] / (float)n + b2[tid]) : 0.f;
    }
}

// ----------------------------------------------------------------- launch
extern "C" void kernel_launch(void* const* d_in, const int* in_sizes, int n_in,
                              void* d_out, int out_size, void* d_ws, size_t ws_size,
                              hipStream_t stream) {
    const float* x   = (const float*)d_in[0];
    const float* W1  = (const float*)d_in[1];
    const float* b1  = (const float*)d_in[2];
    const float* W2  = (const float*)d_in[3];
    const float* b2  = (const float*)d_in[4];
    const int*   src = (const int*)d_in[5];
    const int*   dst = (const int*)d_in[6];
    const int*   gid = (const int*)d_in[7];
    float* out = (float*)d_out;

    // workspace layout (elements, all 4B; float4-aligned where needed)
    int*   cntO    = (int*)d_ws;             //    50,176
    int*   cntI    = cntO + 50176;           //    50,176
    int*   rowptr  = cntI + 50176;           //    50,432 (uses 50,001)
    int*   cursor  = rowptr + 50432;         //    50,176
    int*   csr_src = cursor + 50176;         //   800,000
    float* rsO     = (float*)(csr_src + 800000); // 50,176
    float* rsI     = rsO + 50176;            //    50,176
    float* agg1    = rsI + 50176;            // 6,400,000  (elem off 1,101,312; 16B-aligned)
    float* y       = agg1 + 6400000;         //   800,000
    float* agg2    = y + 800000;             //   800,000  -> total ~36.4 MB

    // zero only the count arrays (401,408 B)
    hipMemsetAsync(d_ws, 0, (size_t)2 * 50176 * sizeof(int), stream);

    k_count<<<(N_EDGES_C + 255) / 256, 256, 0, stream>>>(src, dst, cntO, cntI, N_EDGES_C);
    k_rs<<<(N_NODES_C + 255) / 256, 256, 0, stream>>>(cntO, cntI, rsO, rsI, N_NODES_C);
    k_scan<<<1, 1024, 0, stream>>>(cntI, rowptr, cursor, N_NODES_C);
    k_fill<<<(N_EDGES_C + 255) / 256, 256, 0, stream>>>(src, dst, cursor, csr_src, N_EDGES_C);
    k_agg1<<<(N_NODES_C * 64 + 255) / 256, 256, 0, stream>>>(x, rowptr, csr_src, rsO, rsI, agg1, N_NODES_C);
    k_gemm<<<(N_NODES_C + 31) / 32, 256, 0, stream>>>(agg1, rsO, W1, b1, W2, y, N_NODES_C);
    k_agg2<<<(N_NODES_C * 64 + 255) / 256, 256, 0, stream>>>(y, rowptr, csr_src, agg2, N_NODES_C);
    k_pool<<<N_GRAPHS_C, 256, 0, stream>>>(agg2, rsI, gid, b2, out, N_NODES_C);
}

// Round 3
// 318.239 us; speedup vs baseline: 2.6881x; 1.3621x over previous
//
#include <hip/hip_runtime.h>
#include <hip/hip_bf16.h>

#define N_NODES_C 50000
#define N_EDGES_C 800000
#define N_GRAPHS_C 64
#define SCAN_NB 196   // 196*256 = 50176 >= 50001

// ---------------------------------------------------------------- counts
__global__ void k_count(const int* __restrict__ src, const int* __restrict__ dst,
                        int* __restrict__ cntO, int* __restrict__ cntI, int nE) {
    int e = blockIdx.x * blockDim.x + threadIdx.x;
    if (e < nE) {
        atomicAdd(&cntO[src[e]], 1);
        atomicAdd(&cntI[dst[e]], 1);
    }
}

// ------------------------------------------------- scan phase 1: block sums
__global__ __launch_bounds__(256) void k_scan1(const int* __restrict__ cntI,
                                               int* __restrict__ bsum, int nV) {
    __shared__ int red[4];
    int idx = blockIdx.x * 256 + threadIdx.x;
    int c = (idx < nV) ? cntI[idx] : 0;
#pragma unroll
    for (int off = 32; off > 0; off >>= 1) c += __shfl_down(c, off, 64);
    if ((threadIdx.x & 63) == 0) red[threadIdx.x >> 6] = c;
    __syncthreads();
    if (threadIdx.x == 0) bsum[blockIdx.x] = red[0] + red[1] + red[2] + red[3];
}

// ------------------------------------- scan phase 2: scan 196 partials (1 blk)
__global__ __launch_bounds__(256) void k_scan2(const int* __restrict__ bsum,
                                               int* __restrict__ boff, int nB) {
    __shared__ int part[256];
    int tid = threadIdx.x;
    int v = (tid < nB) ? bsum[tid] : 0;
    part[tid] = v;
    __syncthreads();
    for (int off = 1; off < 256; off <<= 1) {
        int t = (tid >= off) ? part[tid - off] : 0;
        __syncthreads();
        part[tid] += t;
        __syncthreads();
    }
    if (tid < nB) boff[tid] = part[tid] - v;   // exclusive
}

// --------------------- scan phase 3: per-block exclusive scan + rowptr/cursor
//                       also computes rsO/rsI (folded k_rs)
__global__ __launch_bounds__(256) void k_scan3(
    const int* __restrict__ cntI, const int* __restrict__ cntO,
    const int* __restrict__ boff, int* __restrict__ rowptr,
    int* __restrict__ cursor, float* __restrict__ rsO,
    float* __restrict__ rsI, int nV)
{
    __shared__ int part[256];
    int tid = threadIdx.x;
    int idx = blockIdx.x * 256 + tid;
    int c = (idx < nV) ? cntI[idx] : 0;
    part[tid] = c;
    __syncthreads();
    for (int off = 1; off < 256; off <<= 1) {
        int t = (tid >= off) ? part[tid - off] : 0;
        __syncthreads();
        part[tid] += t;
        __syncthreads();
    }
    int excl = boff[blockIdx.x] + part[tid] - c;
    if (idx <= nV) {
        rowptr[idx] = excl;
        if (idx < nV) {
            cursor[idx] = excl;
            rsI[idx] = rsqrtf((float)max(c, 1));
            rsO[idx] = rsqrtf((float)max(cntO[idx], 1));
        }
    }
}

// ------------------------------------------------------------------- CSR fill
__global__ void k_fill(const int* __restrict__ src, const int* __restrict__ dst,
                       int* __restrict__ cursor, int* __restrict__ csr_src, int nE) {
    int e = blockIdx.x * blockDim.x + threadIdx.x;
    if (e < nE) {
        int p = atomicAdd(&cursor[dst[e]], 1);
        csr_src[p] = src[e];
    }
}

// ------------------------------------- layer-1 aggregation: gather-sum per dst
// one wave per node, float2 per lane; agg1[v] = rsI[v] * sum_in x[s]*rsO[s]
__global__ __launch_bounds__(256) void k_agg1(
    const float* __restrict__ x, const int* __restrict__ rowptr,
    const int* __restrict__ csr_src, const float* __restrict__ rsO,
    const float* __restrict__ rsI, float* __restrict__ agg1, int nV)
{
    long long t = (long long)blockIdx.x * blockDim.x + threadIdx.x;
    int v = (int)(t >> 6);
    int lane = (int)(t & 63);
    if (v >= nV) return;
    int beg = rowptr[v], end = rowptr[v + 1];
    float2 acc = make_float2(0.f, 0.f);
    if (beg < end) {
        int s = csr_src[beg];
        for (int j = beg; j < end; ) {
            int sn = (j + 1 < end) ? csr_src[j + 1] : 0;   // prefetch next index
            float w = rsO[s];
            float2 xv = ((const float2*)(x + (size_t)s * 128))[lane];
            acc.x += xv.x * w;
            acc.y += xv.y * w;
            ++j; s = sn;
        }
    }
    float ri = rsI[v];
    ((float2*)(agg1 + (size_t)v * 128))[lane] = make_float2(acc.x * ri, acc.y * ri);
}

// ------------------------------------- fused node GEMMs: h1 = relu(agg1@W1+b1)
//                                       y = (h1*rsO)@W2     (b2 folded into pooling)
__global__ __launch_bounds__(256, 2) void k_gemm(
    const float* __restrict__ agg1, const float* __restrict__ rsO,
    const float* __restrict__ W1, const float* __restrict__ b1,
    const float* __restrict__ W2, float* __restrict__ y, int nV)
{
    __shared__ float Wl[128 * 128];   // 64 KB
    __shared__ float Al[32 * 128];    // 16 KB (A tile, then h1 tile)
    const int tid = threadIdx.x;
    const int row0 = blockIdx.x * 32;

    for (int i = tid * 4; i < 16384; i += 1024)
        *(float4*)&Wl[i] = *(const float4*)&W1[i];
    for (int i = tid * 4; i < 4096; i += 1024) {
        int r = i >> 7, c = i & 127;
        int row = row0 + r;
        float4 v = make_float4(0.f, 0.f, 0.f, 0.f);
        if (row < nV) v = *(const float4*)&agg1[(size_t)row * 128 + c];
        *(float4*)&Al[i] = v;
    }
    __syncthreads();

    const int fg = tid & 15;
    const int rg = tid >> 4;
    const int r0 = rg * 2;
    float acc[2][8];
#pragma unroll
    for (int r = 0; r < 2; ++r)
#pragma unroll
        for (int j = 0; j < 8; ++j) acc[r][j] = 0.f;

#pragma unroll 4
    for (int k = 0; k < 128; ++k) {
        float a0 = Al[r0 * 128 + k];
        float a1 = Al[(r0 + 1) * 128 + k];
        const float* wp = &Wl[k * 128 + fg * 8];
        float4 w0 = *(const float4*)wp;
        float4 w1 = *(const float4*)(wp + 4);
        acc[0][0] += a0 * w0.x; acc[0][1] += a0 * w0.y;
        acc[0][2] += a0 * w0.z; acc[0][3] += a0 * w0.w;
        acc[0][4] += a0 * w1.x; acc[0][5] += a0 * w1.y;
        acc[0][6] += a0 * w1.z; acc[0][7] += a0 * w1.w;
        acc[1][0] += a1 * w0.x; acc[1][1] += a1 * w0.y;
        acc[1][2] += a1 * w0.z; acc[1][3] += a1 * w0.w;
        acc[1][4] += a1 * w1.x; acc[1][5] += a1 * w1.y;
        acc[1][6] += a1 * w1.z; acc[1][7] += a1 * w1.w;
    }
    __syncthreads();
#pragma unroll
    for (int r = 0; r < 2; ++r)
#pragma unroll
        for (int j = 0; j < 8; ++j) {
            float h = acc[r][j] + b1[fg * 8 + j];
            Al[(r0 + r) * 128 + fg * 8 + j] = fmaxf(h, 0.f);
        }
    __syncthreads();

    const int of = tid & 15;
    const int rr = tid >> 4;
    float s0 = 0.f, s1 = 0.f;
#pragma unroll 4
    for (int k = 0; k < 128; ++k) {
        float w = W2[k * 16 + of];
        s0 += Al[rr * 128 + k] * w;
        s1 += Al[(rr + 16) * 128 + k] * w;
    }
    int rowA = row0 + rr, rowB = row0 + rr + 16;
    if (rowA < nV) y[(size_t)rowA * 16 + of] = s0 * rsO[rowA];
    if (rowB < nV) y[(size_t)rowB * 16 + of] = s1 * rsO[rowB];
}

// ------------------------------------- layer-2 aggregation: gather-sum per dst
__global__ __launch_bounds__(256) void k_agg2(
    const float* __restrict__ y, const int* __restrict__ rowptr,
    const int* __restrict__ csr_src, float* __restrict__ agg2, int nV)
{
    long long t = (long long)blockIdx.x * blockDim.x + threadIdx.x;
    int v = (int)(t >> 6);
    int lane = (int)(t & 63);
    if (v >= nV) return;
    int f = lane & 15, g = lane >> 4;
    int beg = rowptr[v], end = rowptr[v + 1];
    float acc = 0.f;
    for (int j = beg + g; j < end; j += 4) {
        int s = csr_src[j];
        acc += y[(size_t)s * 16 + f];
    }
    acc += __shfl_xor(acc, 16, 64);
    acc += __shfl_xor(acc, 32, 64);
    if (g == 0) agg2[(size_t)v * 16 + f] = acc;
}

// ------------------------------------------------- per-graph mean pool (+b2)
__device__ __forceinline__ int lowerb(const int* __restrict__ a, int n, int key) {
    int lo = 0, hi = n;
    while (lo < hi) { int m = (lo + hi) >> 1; if (a[m] < key) lo = m + 1; else hi = m; }
    return lo;
}

__global__ __launch_bounds__(256) void k_pool(
    const float* __restrict__ agg2, const float* __restrict__ rsI,
    const int* __restrict__ gid, const float* __restrict__ b2,
    float* __restrict__ out, int nV)
{
    __shared__ float red[256][16];
    const int g = blockIdx.x;
    const int tid = threadIdx.x;
    const int lo = lowerb(gid, nV, g);
    const int hi = lowerb(gid, nV, g + 1);

    float acc[16];
#pragma unroll
    for (int f = 0; f < 16; ++f) acc[f] = 0.f;

    for (int v = lo + tid; v < hi; v += 256) {
        float w = rsI[v];
        const float4* p = (const float4*)(agg2 + (size_t)v * 16);
        float4 a = p[0], b = p[1], c = p[2], d = p[3];
        acc[0] += a.x * w; acc[1] += a.y * w; acc[2]  += a.z * w; acc[3]  += a.w * w;
        acc[4] += b.x * w; acc[5] += b.y * w; acc[6]  += b.z * w; acc[7]  += b.w * w;
        acc[8] += c.x * w; acc[9] += c.y * w; acc[10] += c.z * w; acc[11] += c.w * w;
        acc[12] += d.x * w; acc[13] += d.y * w; acc[14] += d.z * w; acc[15] += d.w * w;
    }
#pragma unroll
    for (int f = 0; f < 16; ++f) red[tid][f] = acc[f];
    __syncthreads();
    for (int s = 128; s > 0; s >>= 1) {
        if (tid < s)
#pragma unroll
            for (int f = 0; f < 16; ++f) red[tid][f] += red[tid + s][f];
        __syncthreads();
    }
    if (tid < 16) {
        int n = hi - lo;
        out[g * 16 + tid] = (n > 0) ? (red[0][tid] / (float)n + b2[tid]) : 0.f;
    }
}

// ----------------------------------------------------------------- launch
extern "C" void kernel_launch(void* const* d_in, const int* in_sizes, int n_in,
                              void* d_out, int out_size, void* d_ws, size_t ws_size,
                              hipStream_t stream) {
    const float* x   = (const float*)d_in[0];
    const float* W1  = (const float*)d_in[1];
    const float* b1  = (const float*)d_in[2];
    const float* W2  = (const float*)d_in[3];
    const float* b2  = (const float*)d_in[4];
    const int*   src = (const int*)d_in[5];
    const int*   dst = (const int*)d_in[6];
    const int*   gid = (const int*)d_in[7];
    float* out = (float*)d_out;

    // workspace layout (elements, all 4B)
    int*   cntO    = (int*)d_ws;             //    50,176
    int*   cntI    = cntO + 50176;           //    50,176
    int*   rowptr  = cntI + 50176;           //    50,432 (uses 50,001)
    int*   cursor  = rowptr + 50432;         //    50,176
    int*   csr_src = cursor + 50176;         //   800,000
    int*   bsum    = csr_src + 800000;       //       256
    int*   boff    = bsum + 256;             //       256
    float* rsO     = (float*)(boff + 256);   //    50,176
    float* rsI     = rsO + 50176;            //    50,176
    float* agg1    = rsI + 50176;            // 6,400,000
    float* y       = agg1 + 6400000;         //   800,000
    float* agg2    = y + 800000;             //   800,000

    // zero only the count arrays (401,408 B)
    hipMemsetAsync(d_ws, 0, (size_t)2 * 50176 * sizeof(int), stream);

    k_count<<<(N_EDGES_C + 255) / 256, 256, 0, stream>>>(src, dst, cntO, cntI, N_EDGES_C);
    k_scan1<<<SCAN_NB, 256, 0, stream>>>(cntI, bsum, N_NODES_C);
    k_scan2<<<1, 256, 0, stream>>>(bsum, boff, SCAN_NB);
    k_scan3<<<SCAN_NB, 256, 0, stream>>>(cntI, cntO, boff, rowptr, cursor, rsO, rsI, N_NODES_C);
    k_fill<<<(N_EDGES_C + 255) / 256, 256, 0, stream>>>(src, dst, cursor, csr_src, N_EDGES_C);
    k_agg1<<<(N_NODES_C * 64 + 255) / 256, 256, 0, stream>>>(x, rowptr, csr_src, rsO, rsI, agg1, N_NODES_C);
    k_gemm<<<(N_NODES_C + 31) / 32, 256, 0, stream>>>(agg1, rsO, W1, b1, W2, y, N_NODES_C);
    k_agg2<<<(N_NODES_C * 64 + 255) / 256, 256, 0, stream>>>(y, rowptr, csr_src, agg2, N_NODES_C);
    k_pool<<<N_GRAPHS_C, 256, 0, stream>>>(agg2, rsI, gid, b2, out, N_NODES_C);
}

// Round 4
// 273.055 us; speedup vs baseline: 3.1329x; 1.1655x over previous
//
#include <hip/hip_runtime.h>
#include <hip/hip_bf16.h>

#define N_NODES_C 50000
#define N_EDGES_C 800000
#define N_GRAPHS_C 64
#define SCAN_NB 196   // 196*256 = 50176 >= 50001

__device__ __forceinline__ unsigned short f2bf(float f) {
    unsigned u = __float_as_uint(f);
    unsigned r = (u + 0x7FFFu + ((u >> 16) & 1u)) >> 16;   // RNE
    return (unsigned short)r;
}

// ---------------------------------------------------------------- counts
__global__ void k_count(const int* __restrict__ src, const int* __restrict__ dst,
                        int* __restrict__ cntO, int* __restrict__ cntI, int nE) {
    int e = blockIdx.x * blockDim.x + threadIdx.x;
    if (e < nE) {
        atomicAdd(&cntO[src[e]], 1);
        atomicAdd(&cntI[dst[e]], 1);
    }
}

// ------------------------------------------------- scan phase 1: block sums
__global__ __launch_bounds__(256) void k_scan1(const int* __restrict__ cntI,
                                               int* __restrict__ bsum, int nV) {
    __shared__ int red[4];
    int idx = blockIdx.x * 256 + threadIdx.x;
    int c = (idx < nV) ? cntI[idx] : 0;
#pragma unroll
    for (int off = 32; off > 0; off >>= 1) c += __shfl_down(c, off, 64);
    if ((threadIdx.x & 63) == 0) red[threadIdx.x >> 6] = c;
    __syncthreads();
    if (threadIdx.x == 0) bsum[blockIdx.x] = red[0] + red[1] + red[2] + red[3];
}

// ------------------------------------- scan phase 2: scan 196 partials (1 blk)
__global__ __launch_bounds__(256) void k_scan2(const int* __restrict__ bsum,
                                               int* __restrict__ boff, int nB) {
    __shared__ int part[256];
    int tid = threadIdx.x;
    int v = (tid < nB) ? bsum[tid] : 0;
    part[tid] = v;
    __syncthreads();
    for (int off = 1; off < 256; off <<= 1) {
        int t = (tid >= off) ? part[tid - off] : 0;
        __syncthreads();
        part[tid] += t;
        __syncthreads();
    }
    if (tid < nB) boff[tid] = part[tid] - v;   // exclusive
}

// --------------------- scan phase 3: per-block exclusive scan + rowptr/cursor
__global__ __launch_bounds__(256) void k_scan3(
    const int* __restrict__ cntI, const int* __restrict__ cntO,
    const int* __restrict__ boff, int* __restrict__ rowptr,
    int* __restrict__ cursor, float* __restrict__ rsO,
    float* __restrict__ rsI, int nV)
{
    __shared__ int part[256];
    int tid = threadIdx.x;
    int idx = blockIdx.x * 256 + tid;
    int c = (idx < nV) ? cntI[idx] : 0;
    part[tid] = c;
    __syncthreads();
    for (int off = 1; off < 256; off <<= 1) {
        int t = (tid >= off) ? part[tid - off] : 0;
        __syncthreads();
        part[tid] += t;
        __syncthreads();
    }
    int excl = boff[blockIdx.x] + part[tid] - c;
    if (idx <= nV) {
        rowptr[idx] = excl;
        if (idx < nV) {
            cursor[idx] = excl;
            rsI[idx] = rsqrtf((float)max(c, 1));
            rsO[idx] = rsqrtf((float)max(cntO[idx], 1));
        }
    }
}

// ------------------------------------------------------------------- CSR fill
__global__ void k_fill(const int* __restrict__ src, const int* __restrict__ dst,
                       int* __restrict__ cursor, int* __restrict__ csr_src, int nE) {
    int e = blockIdx.x * blockDim.x + threadIdx.x;
    if (e < nE) {
        int p = atomicAdd(&cursor[dst[e]], 1);
        csr_src[p] = src[e];
    }
}

// --------------------------------------------- xs = bf16(x * rsO), 256 B rows
__global__ __launch_bounds__(256) void k_prep(
    const float* __restrict__ x, const float* __restrict__ rsO,
    unsigned short* __restrict__ xs, int nV)
{
    int t = blockIdx.x * 256 + threadIdx.x;
    if (t >= nV * 32) return;
    int v = t >> 5, q = t & 31;
    float w = rsO[v];
    float4 a = ((const float4*)(x + (size_t)v * 128))[q];
    ushort4 o;
    o.x = f2bf(a.x * w); o.y = f2bf(a.y * w);
    o.z = f2bf(a.z * w); o.w = f2bf(a.w * w);
    ((ushort4*)(xs + (size_t)v * 128))[q] = o;
}

// ---------------- layer-1 aggregation (bf16 gather, 4 edges per wave-load)
// 16-lane group g handles edge beg+it*4+g; each group loads a full 256 B row.
__global__ __launch_bounds__(256) void k_agg1b(
    const unsigned short* __restrict__ xs, const int* __restrict__ rowptr,
    const int* __restrict__ csr_src, const float* __restrict__ rsI,
    float* __restrict__ agg1, int nV)
{
    long long t = (long long)blockIdx.x * blockDim.x + threadIdx.x;
    int v = (int)(t >> 6);
    int lane = (int)(t & 63);
    if (v >= nV) return;
    int g = lane >> 4, fl = lane & 15;
    int beg = rowptr[v], end = rowptr[v + 1];
    float acc[8];
#pragma unroll
    for (int k = 0; k < 8; ++k) acc[k] = 0.f;

    for (int j = beg + g; j < end; j += 4) {
        int s = csr_src[j];
        uint4 w = *(const uint4*)(xs + (size_t)s * 128 + fl * 8);
        acc[0] += __uint_as_float(w.x << 16);
        acc[1] += __uint_as_float(w.x & 0xFFFF0000u);
        acc[2] += __uint_as_float(w.y << 16);
        acc[3] += __uint_as_float(w.y & 0xFFFF0000u);
        acc[4] += __uint_as_float(w.z << 16);
        acc[5] += __uint_as_float(w.z & 0xFFFF0000u);
        acc[6] += __uint_as_float(w.w << 16);
        acc[7] += __uint_as_float(w.w & 0xFFFF0000u);
    }
#pragma unroll
    for (int k = 0; k < 8; ++k) {
        acc[k] += __shfl_xor(acc[k], 16, 64);
        acc[k] += __shfl_xor(acc[k], 32, 64);
    }
    float ri = rsI[v];
    if (g < 2) {
        float4 o = make_float4(acc[g * 4] * ri, acc[g * 4 + 1] * ri,
                               acc[g * 4 + 2] * ri, acc[g * 4 + 3] * ri);
        ((float4*)(agg1 + (size_t)v * 128 + fl * 8))[g] = o;
    }
}

// --------------- fp32 fallback (used only if ws too small for xs)
__global__ __launch_bounds__(256) void k_agg1(
    const float* __restrict__ x, const int* __restrict__ rowptr,
    const int* __restrict__ csr_src, const float* __restrict__ rsO,
    const float* __restrict__ rsI, float* __restrict__ agg1, int nV)
{
    long long t = (long long)blockIdx.x * blockDim.x + threadIdx.x;
    int v = (int)(t >> 6);
    int lane = (int)(t & 63);
    if (v >= nV) return;
    int beg = rowptr[v], end = rowptr[v + 1];
    float2 acc = make_float2(0.f, 0.f);
    for (int j = beg; j < end; ++j) {
        int s = csr_src[j];
        float w = rsO[s];
        float2 xv = ((const float2*)(x + (size_t)s * 128))[lane];
        acc.x += xv.x * w;
        acc.y += xv.y * w;
    }
    float ri = rsI[v];
    ((float2*)(agg1 + (size_t)v * 128))[lane] = make_float2(acc.x * ri, acc.y * ri);
}

// ------------------------------------- fused node GEMMs: h1 = relu(agg1@W1+b1)
//                                       y = (h1*rsO)@W2     (b2 folded into pooling)
__global__ __launch_bounds__(256, 2) void k_gemm(
    const float* __restrict__ agg1, const float* __restrict__ rsO,
    const float* __restrict__ W1, const float* __restrict__ b1,
    const float* __restrict__ W2, float* __restrict__ y, int nV)
{
    __shared__ float Wl[128 * 128];   // 64 KB
    __shared__ float Al[32 * 128];    // 16 KB
    const int tid = threadIdx.x;
    const int row0 = blockIdx.x * 32;

    for (int i = tid * 4; i < 16384; i += 1024)
        *(float4*)&Wl[i] = *(const float4*)&W1[i];
    for (int i = tid * 4; i < 4096; i += 1024) {
        int r = i >> 7, c = i & 127;
        int row = row0 + r;
        float4 v = make_float4(0.f, 0.f, 0.f, 0.f);
        if (row < nV) v = *(const float4*)&agg1[(size_t)row * 128 + c];
        *(float4*)&Al[i] = v;
    }
    __syncthreads();

    const int fg = tid & 15;
    const int rg = tid >> 4;
    const int r0 = rg * 2;
    float acc[2][8];
#pragma unroll
    for (int r = 0; r < 2; ++r)
#pragma unroll
        for (int j = 0; j < 8; ++j) acc[r][j] = 0.f;

#pragma unroll 4
    for (int k = 0; k < 128; ++k) {
        float a0 = Al[r0 * 128 + k];
        float a1 = Al[(r0 + 1) * 128 + k];
        const float* wp = &Wl[k * 128 + fg * 8];
        float4 w0 = *(const float4*)wp;
        float4 w1 = *(const float4*)(wp + 4);
        acc[0][0] += a0 * w0.x; acc[0][1] += a0 * w0.y;
        acc[0][2] += a0 * w0.z; acc[0][3] += a0 * w0.w;
        acc[0][4] += a0 * w1.x; acc[0][5] += a0 * w1.y;
        acc[0][6] += a0 * w1.z; acc[0][7] += a0 * w1.w;
        acc[1][0] += a1 * w0.x; acc[1][1] += a1 * w0.y;
        acc[1][2] += a1 * w0.z; acc[1][3] += a1 * w0.w;
        acc[1][4] += a1 * w1.x; acc[1][5] += a1 * w1.y;
        acc[1][6] += a1 * w1.z; acc[1][7] += a1 * w1.w;
    }
    __syncthreads();
#pragma unroll
    for (int r = 0; r < 2; ++r)
#pragma unroll
        for (int j = 0; j < 8; ++j) {
            float h = acc[r][j] + b1[fg * 8 + j];
            Al[(r0 + r) * 128 + fg * 8 + j] = fmaxf(h, 0.f);
        }
    __syncthreads();

    const int of = tid & 15;
    const int rr = tid >> 4;
    float s0 = 0.f, s1 = 0.f;
#pragma unroll 4
    for (int k = 0; k < 128; ++k) {
        float w = W2[k * 16 + of];
        s0 += Al[rr * 128 + k] * w;
        s1 += Al[(rr + 16) * 128 + k] * w;
    }
    int rowA = row0 + rr, rowB = row0 + rr + 16;
    if (rowA < nV) y[(size_t)rowA * 16 + of] = s0 * rsO[rowA];
    if (rowB < nV) y[(size_t)rowB * 16 + of] = s1 * rsO[rowB];
}

// ------------------------------------- layer-2 aggregation: gather-sum per dst
__global__ __launch_bounds__(256) void k_agg2(
    const float* __restrict__ y, const int* __restrict__ rowptr,
    const int* __restrict__ csr_src, float* __restrict__ agg2, int nV)
{
    long long t = (long long)blockIdx.x * blockDim.x + threadIdx.x;
    int v = (int)(t >> 6);
    int lane = (int)(t & 63);
    if (v >= nV) return;
    int f = lane & 15, g = lane >> 4;
    int beg = rowptr[v], end = rowptr[v + 1];
    float acc = 0.f;
    for (int j = beg + g; j < end; j += 4) {
        int s = csr_src[j];
        acc += y[(size_t)s * 16 + f];
    }
    acc += __shfl_xor(acc, 16, 64);
    acc += __shfl_xor(acc, 32, 64);
    if (g == 0) agg2[(size_t)v * 16 + f] = acc;
}

// ------------------------------------------------- per-graph mean pool (+b2)
__device__ __forceinline__ int lowerb(const int* __restrict__ a, int n, int key) {
    int lo = 0, hi = n;
    while (lo < hi) { int m = (lo + hi) >> 1; if (a[m] < key) lo = m + 1; else hi = m; }
    return lo;
}

__global__ __launch_bounds__(256) void k_pool(
    const float* __restrict__ agg2, const float* __restrict__ rsI,
    const int* __restrict__ gid, const float* __restrict__ b2,
    float* __restrict__ out, int nV)
{
    __shared__ float red[256][16];
    const int g = blockIdx.x;
    const int tid = threadIdx.x;
    const int lo = lowerb(gid, nV, g);
    const int hi = lowerb(gid, nV, g + 1);

    float acc[16];
#pragma unroll
    for (int f = 0; f < 16; ++f) acc[f] = 0.f;

    for (int v = lo + tid; v < hi; v += 256) {
        float w = rsI[v];
        const float4* p = (const float4*)(agg2 + (size_t)v * 16);
        float4 a = p[0], b = p[1], c = p[2], d = p[3];
        acc[0] += a.x * w; acc[1] += a.y * w; acc[2]  += a.z * w; acc[3]  += a.w * w;
        acc[4] += b.x * w; acc[5] += b.y * w; acc[6]  += b.z * w; acc[7]  += b.w * w;
        acc[8] += c.x * w; acc[9] += c.y * w; acc[10] += c.z * w; acc[11] += c.w * w;
        acc[12] += d.x * w; acc[13] += d.y * w; acc[14] += d.z * w; acc[15] += d.w * w;
    }
#pragma unroll
    for (int f = 0; f < 16; ++f) red[tid][f] = acc[f];
    __syncthreads();
    for (int s = 128; s > 0; s >>= 1) {
        if (tid < s)
#pragma unroll
            for (int f = 0; f < 16; ++f) red[tid][f] += red[tid + s][f];
        __syncthreads();
    }
    if (tid < 16) {
        int n = hi - lo;
        out[g * 16 + tid] = (n > 0) ? (red[0][tid] / (float)n + b2[tid]) : 0.f;
    }
}

// ----------------------------------------------------------------- launch
extern "C" void kernel_launch(void* const* d_in, const int* in_sizes, int n_in,
                              void* d_out, int out_size, void* d_ws, size_t ws_size,
                              hipStream_t stream) {
    const float* x   = (const float*)d_in[0];
    const float* W1  = (const float*)d_in[1];
    const float* b1  = (const float*)d_in[2];
    const float* W2  = (const float*)d_in[3];
    const float* b2  = (const float*)d_in[4];
    const int*   src = (const int*)d_in[5];
    const int*   dst = (const int*)d_in[6];
    const int*   gid = (const int*)d_in[7];
    float* out = (float*)d_out;

    // workspace layout (elements of 4B unless noted)
    int*   cntO    = (int*)d_ws;                 //    50,176
    int*   cntI    = cntO + 50176;               //    50,176
    int*   rowptr  = cntI + 50176;               //    50,432 (uses 50,001)
    int*   cursor  = rowptr + 50432;             //    50,176
    int*   csr_src = cursor + 50176;             //   800,000
    int*   bsum    = csr_src + 800000;           //       256
    int*   boff    = bsum + 256;                 //       256
    float* rsO     = (float*)(boff + 256);       //    50,176
    float* rsI     = rsO + 50176;                //    50,176
    float* agg1    = rsI + 50176;                // 6,400,000 fp32 (25.6 MB)
    unsigned short* xs = (unsigned short*)(agg1 + 6400000);  // 6,400,000 bf16 (12.8 MB)
    float* y       = (float*)(xs + 6400000);     //   800,000
    float* agg2    = y + 800000;                 //   800,000
    size_t need = (size_t)((char*)(agg2 + 800000) - (char*)d_ws);

    hipMemsetAsync(d_ws, 0, (size_t)2 * 50176 * sizeof(int), stream);

    k_count<<<(N_EDGES_C + 255) / 256, 256, 0, stream>>>(src, dst, cntO, cntI, N_EDGES_C);
    k_scan1<<<SCAN_NB, 256, 0, stream>>>(cntI, bsum, N_NODES_C);
    k_scan2<<<1, 256, 0, stream>>>(bsum, boff, SCAN_NB);
    k_scan3<<<SCAN_NB, 256, 0, stream>>>(cntI, cntO, boff, rowptr, cursor, rsO, rsI, N_NODES_C);
    k_fill<<<(N_EDGES_C + 255) / 256, 256, 0, stream>>>(src, dst, cursor, csr_src, N_EDGES_C);

    if (ws_size >= need) {
        k_prep<<<(N_NODES_C * 32 + 255) / 256, 256, 0, stream>>>(x, rsO, xs, N_NODES_C);
        k_agg1b<<<(N_NODES_C * 64 + 255) / 256, 256, 0, stream>>>(xs, rowptr, csr_src, rsI, agg1, N_NODES_C);
    } else {
        // fp32 fallback: reuse xs region's absence — y/agg2 move down
        y    = (float*)xs;
        agg2 = y + 800000;
        k_agg1<<<(N_NODES_C * 64 + 255) / 256, 256, 0, stream>>>(x, rowptr, csr_src, rsO, rsI, agg1, N_NODES_C);
    }
    k_gemm<<<(N_NODES_C + 31) / 32, 256, 0, stream>>>(agg1, rsO, W1, b1, W2, y, N_NODES_C);
    k_agg2<<<(N_NODES_C * 64 + 255) / 256, 256, 0, stream>>>(y, rowptr, csr_src, agg2, N_NODES_C);
    k_pool<<<N_GRAPHS_C, 256, 0, stream>>>(agg2, rsI, gid, b2, out, N_NODES_C);
}

// Round 5
// 222.082 us; speedup vs baseline: 3.8520x; 1.2295x over previous
//
#include <hip/hip_runtime.h>
#include <hip/hip_bf16.h>

#define N_NODES_C 50000
#define N_EDGES_C 800000
#define N_GRAPHS_C 64
#define SCAN_NB 196   // 196*256 = 50176 >= 50001

typedef __attribute__((ext_vector_type(8))) short bf16x8;
typedef __attribute__((ext_vector_type(4))) float f32x4;

__device__ __forceinline__ unsigned short f2bf(float f) {
    unsigned u = __float_as_uint(f);
    unsigned r = (u + 0x7FFFu + ((u >> 16) & 1u)) >> 16;   // RNE
    return (unsigned short)r;
}

// ---------------------------------------------------------------- counts
__global__ void k_count(const int* __restrict__ src, const int* __restrict__ dst,
                        int* __restrict__ cntO, int* __restrict__ cntI, int nE) {
    int e = blockIdx.x * blockDim.x + threadIdx.x;
    if (e < nE) {
        atomicAdd(&cntO[src[e]], 1);
        atomicAdd(&cntI[dst[e]], 1);
    }
}

// ------------------------------------------------- scan phase 1: block sums
__global__ __launch_bounds__(256) void k_scan1(const int* __restrict__ cntI,
                                               int* __restrict__ bsum, int nV) {
    __shared__ int red[4];
    int idx = blockIdx.x * 256 + threadIdx.x;
    int c = (idx < nV) ? cntI[idx] : 0;
#pragma unroll
    for (int off = 32; off > 0; off >>= 1) c += __shfl_down(c, off, 64);
    if ((threadIdx.x & 63) == 0) red[threadIdx.x >> 6] = c;
    __syncthreads();
    if (threadIdx.x == 0) bsum[blockIdx.x] = red[0] + red[1] + red[2] + red[3];
}

// ------------------------------------- scan phase 2: scan 196 partials (1 blk)
__global__ __launch_bounds__(256) void k_scan2(const int* __restrict__ bsum,
                                               int* __restrict__ boff, int nB) {
    __shared__ int part[256];
    int tid = threadIdx.x;
    int v = (tid < nB) ? bsum[tid] : 0;
    part[tid] = v;
    __syncthreads();
    for (int off = 1; off < 256; off <<= 1) {
        int t = (tid >= off) ? part[tid - off] : 0;
        __syncthreads();
        part[tid] += t;
        __syncthreads();
    }
    if (tid < nB) boff[tid] = part[tid] - v;   // exclusive
}

// --------------------- scan phase 3: per-block exclusive scan + rowptr/cursor
__global__ __launch_bounds__(256) void k_scan3(
    const int* __restrict__ cntI, const int* __restrict__ cntO,
    const int* __restrict__ boff, int* __restrict__ rowptr,
    int* __restrict__ cursor, float* __restrict__ rsO,
    float* __restrict__ rsI, int nV)
{
    __shared__ int part[256];
    int tid = threadIdx.x;
    int idx = blockIdx.x * 256 + tid;
    int c = (idx < nV) ? cntI[idx] : 0;
    part[tid] = c;
    __syncthreads();
    for (int off = 1; off < 256; off <<= 1) {
        int t = (tid >= off) ? part[tid - off] : 0;
        __syncthreads();
        part[tid] += t;
        __syncthreads();
    }
    int excl = boff[blockIdx.x] + part[tid] - c;
    if (idx <= nV) {
        rowptr[idx] = excl;
        if (idx < nV) {
            cursor[idx] = excl;
            rsI[idx] = rsqrtf((float)max(c, 1));
            rsO[idx] = rsqrtf((float)max(cntO[idx], 1));
        }
    }
}

// ------------------------------------------------------------------- CSR fill
__global__ void k_fill(const int* __restrict__ src, const int* __restrict__ dst,
                       int* __restrict__ cursor, int* __restrict__ csr_src, int nE) {
    int e = blockIdx.x * blockDim.x + threadIdx.x;
    if (e < nE) {
        int p = atomicAdd(&cursor[dst[e]], 1);
        csr_src[p] = src[e];
    }
}

// --------------------------------------------- xs = bf16(x * rsO), 256 B rows
__global__ __launch_bounds__(256) void k_prep(
    const float* __restrict__ x, const float* __restrict__ rsO,
    unsigned short* __restrict__ xs, int nV)
{
    int t = blockIdx.x * 256 + threadIdx.x;
    if (t >= nV * 32) return;
    int v = t >> 5, q = t & 31;
    float w = rsO[v];
    float4 a = ((const float4*)(x + (size_t)v * 128))[q];
    ushort4 o;
    o.x = f2bf(a.x * w); o.y = f2bf(a.y * w);
    o.z = f2bf(a.z * w); o.w = f2bf(a.w * w);
    ((ushort4*)(xs + (size_t)v * 128))[q] = o;
}

// ------------- W1/W2 -> bf16 fragment order for mfma_f32_16x16x32_bf16 B-frags
// w1f[((kk*8+nt)*64+l)*8+i] = W1[kk*32+(l>>4)*8+i][nt*16+(l&15)]
// w2f[(kk*64+l)*8+i]        = W2[kk*32+(l>>4)*8+i][l&15]
__global__ __launch_bounds__(256) void k_wconv(
    const float* __restrict__ W1, const float* __restrict__ W2,
    unsigned short* __restrict__ w1f, unsigned short* __restrict__ w2f)
{
    int t = blockIdx.x * 256 + threadIdx.x;
    if (t < 2048) {
        int kk = t >> 9, nt = (t >> 6) & 7, l = t & 63;
        int kb = kk * 32 + ((l >> 4) << 3), n = nt * 16 + (l & 15);
        ushort4 lo, hi;
        lo.x = f2bf(W1[(kb + 0) * 128 + n]); lo.y = f2bf(W1[(kb + 1) * 128 + n]);
        lo.z = f2bf(W1[(kb + 2) * 128 + n]); lo.w = f2bf(W1[(kb + 3) * 128 + n]);
        hi.x = f2bf(W1[(kb + 4) * 128 + n]); hi.y = f2bf(W1[(kb + 5) * 128 + n]);
        hi.z = f2bf(W1[(kb + 6) * 128 + n]); hi.w = f2bf(W1[(kb + 7) * 128 + n]);
        ((ushort4*)(w1f + t * 8))[0] = lo;
        ((ushort4*)(w1f + t * 8))[1] = hi;
    } else if (t < 2304) {
        int t2 = t - 2048;
        int kk = t2 >> 6, l = t2 & 63;
        int kb = kk * 32 + ((l >> 4) << 3), n = l & 15;
        ushort4 lo, hi;
        lo.x = f2bf(W2[(kb + 0) * 16 + n]); lo.y = f2bf(W2[(kb + 1) * 16 + n]);
        lo.z = f2bf(W2[(kb + 2) * 16 + n]); lo.w = f2bf(W2[(kb + 3) * 16 + n]);
        hi.x = f2bf(W2[(kb + 4) * 16 + n]); hi.y = f2bf(W2[(kb + 5) * 16 + n]);
        hi.z = f2bf(W2[(kb + 6) * 16 + n]); hi.w = f2bf(W2[(kb + 7) * 16 + n]);
        ((ushort4*)(w2f + t2 * 8))[0] = lo;
        ((ushort4*)(w2f + t2 * 8))[1] = hi;
    }
}

// ---------------- layer-1 aggregation (bf16 gather, 4 edges per wave-load)
// writes agg1 as bf16 (fp32 accumulate, single rounding)
__global__ __launch_bounds__(256) void k_agg1b(
    const unsigned short* __restrict__ xs, const int* __restrict__ rowptr,
    const int* __restrict__ csr_src, const float* __restrict__ rsI,
    unsigned short* __restrict__ agg1b, int nV)
{
    long long t = (long long)blockIdx.x * blockDim.x + threadIdx.x;
    int v = (int)(t >> 6);
    int lane = (int)(t & 63);
    if (v >= nV) return;
    int g = lane >> 4, fl = lane & 15;
    int beg = rowptr[v], end = rowptr[v + 1];
    float acc[8];
#pragma unroll
    for (int k = 0; k < 8; ++k) acc[k] = 0.f;

    for (int j = beg + g; j < end; j += 4) {
        int s = csr_src[j];
        uint4 w = *(const uint4*)(xs + (size_t)s * 128 + fl * 8);
        acc[0] += __uint_as_float(w.x << 16);
        acc[1] += __uint_as_float(w.x & 0xFFFF0000u);
        acc[2] += __uint_as_float(w.y << 16);
        acc[3] += __uint_as_float(w.y & 0xFFFF0000u);
        acc[4] += __uint_as_float(w.z << 16);
        acc[5] += __uint_as_float(w.z & 0xFFFF0000u);
        acc[6] += __uint_as_float(w.w << 16);
        acc[7] += __uint_as_float(w.w & 0xFFFF0000u);
    }
#pragma unroll
    for (int k = 0; k < 8; ++k) {
        acc[k] += __shfl_xor(acc[k], 16, 64);
        acc[k] += __shfl_xor(acc[k], 32, 64);
    }
    float ri = rsI[v];
    if (g < 2) {
        ushort4 o;
        o.x = f2bf(acc[g * 4 + 0] * ri);
        o.y = f2bf(acc[g * 4 + 1] * ri);
        o.z = f2bf(acc[g * 4 + 2] * ri);
        o.w = f2bf(acc[g * 4 + 3] * ri);
        *(ushort4*)(agg1b + (size_t)v * 128 + fl * 8 + g * 4) = o;
    }
}

// -------------------- fused MFMA GEMMs: h1 = relu(agg1b@W1+b1); y = (h1@W2)*rsO
// block = 256 thr (4 waves); wave w owns rows row0+w*16 .. +15
__global__ __launch_bounds__(256) void k_mfma(
    const unsigned short* __restrict__ agg1b, const float* __restrict__ b1,
    const unsigned short* __restrict__ w1f, const unsigned short* __restrict__ w2f,
    const float* __restrict__ rsO, float* __restrict__ y, int nV)
{
    __shared__ __align__(16) unsigned short h1[64 * 136];   // padded: 272 B rows
    const int tid = threadIdx.x;
    const int w = tid >> 6, l = tid & 63;
    const int lr = l & 15, lg = l >> 4;
    const int row0 = blockIdx.x * 64;

    // layer-1: A-frags from global (L2-resident), B-frags fragment-ordered
    bf16x8 a[4];
    const unsigned short* abase = agg1b + (size_t)(row0 + w * 16 + lr) * 128 + lg * 8;
#pragma unroll
    for (int kk = 0; kk < 4; ++kk)
        a[kk] = *(const bf16x8*)(abase + kk * 32);

    f32x4 acc[8];
#pragma unroll
    for (int nt = 0; nt < 8; ++nt) acc[nt] = (f32x4){0.f, 0.f, 0.f, 0.f};

#pragma unroll
    for (int nt = 0; nt < 8; ++nt)
#pragma unroll
        for (int kk = 0; kk < 4; ++kk) {
            bf16x8 b = *(const bf16x8*)(w1f + ((kk * 8 + nt) * 64 + l) * 8);
            acc[nt] = __builtin_amdgcn_mfma_f32_16x16x32_bf16(a[kk], b, acc[nt], 0, 0, 0);
        }

    // epilogue 1: +b1, relu, bf16 -> LDS (C/D map: col=lane&15, row=(lane>>4)*4+i)
#pragma unroll
    for (int nt = 0; nt < 8; ++nt) {
        float bb = b1[nt * 16 + lr];
#pragma unroll
        for (int i = 0; i < 4; ++i) {
            float h = fmaxf(acc[nt][i] + bb, 0.f);
            h1[(w * 16 + lg * 4 + i) * 136 + nt * 16 + lr] = f2bf(h);
        }
    }
    __syncthreads();

    // layer-2: A-frags from LDS h1, B = w2f; N=16, K=128
    f32x4 acc2 = (f32x4){0.f, 0.f, 0.f, 0.f};
#pragma unroll
    for (int kk = 0; kk < 4; ++kk) {
        bf16x8 a2 = *(const bf16x8*)(&h1[(w * 16 + lr) * 136 + kk * 32 + lg * 8]);
        bf16x8 b2 = *(const bf16x8*)(w2f + (kk * 64 + l) * 8);
        acc2 = __builtin_amdgcn_mfma_f32_16x16x32_bf16(a2, b2, acc2, 0, 0, 0);
    }
#pragma unroll
    for (int i = 0; i < 4; ++i) {
        int r = row0 + w * 16 + lg * 4 + i;
        if (r < nV) y[(size_t)r * 16 + lr] = acc2[i] * rsO[r];
    }
}

// ------------------------------------- layer-2 aggregation: gather-sum per dst
__global__ __launch_bounds__(256) void k_agg2(
    const float* __restrict__ y, const int* __restrict__ rowptr,
    const int* __restrict__ csr_src, float* __restrict__ agg2, int nV)
{
    long long t = (long long)blockIdx.x * blockDim.x + threadIdx.x;
    int v = (int)(t >> 6);
    int lane = (int)(t & 63);
    if (v >= nV) return;
    int f = lane & 15, g = lane >> 4;
    int beg = rowptr[v], end = rowptr[v + 1];
    float acc = 0.f;
    for (int j = beg + g; j < end; j += 4) {
        int s = csr_src[j];
        acc += y[(size_t)s * 16 + f];
    }
    acc += __shfl_xor(acc, 16, 64);
    acc += __shfl_xor(acc, 32, 64);
    if (g == 0) agg2[(size_t)v * 16 + f] = acc;
}

// ------------------------------------------------- per-graph mean pool (+b2)
__device__ __forceinline__ int lowerb(const int* __restrict__ a, int n, int key) {
    int lo = 0, hi = n;
    while (lo < hi) { int m = (lo + hi) >> 1; if (a[m] < key) lo = m + 1; else hi = m; }
    return lo;
}

__global__ __launch_bounds__(256) void k_pool(
    const float* __restrict__ agg2, const float* __restrict__ rsI,
    const int* __restrict__ gid, const float* __restrict__ b2,
    float* __restrict__ out, int nV)
{
    __shared__ float red[256][16];
    const int g = blockIdx.x;
    const int tid = threadIdx.x;
    const int lo = lowerb(gid, nV, g);
    const int hi = lowerb(gid, nV, g + 1);

    float acc[16];
#pragma unroll
    for (int f = 0; f < 16; ++f) acc[f] = 0.f;

    for (int v = lo + tid; v < hi; v += 256) {
        float w = rsI[v];
        const float4* p = (const float4*)(agg2 + (size_t)v * 16);
        float4 a = p[0], b = p[1], c = p[2], d = p[3];
        acc[0] += a.x * w; acc[1] += a.y * w; acc[2]  += a.z * w; acc[3]  += a.w * w;
        acc[4] += b.x * w; acc[5] += b.y * w; acc[6]  += b.z * w; acc[7]  += b.w * w;
        acc[8] += c.x * w; acc[9] += c.y * w; acc[10] += c.z * w; acc[11] += c.w * w;
        acc[12] += d.x * w; acc[13] += d.y * w; acc[14] += d.z * w; acc[15] += d.w * w;
    }
#pragma unroll
    for (int f = 0; f < 16; ++f) red[tid][f] = acc[f];
    __syncthreads();
    for (int s = 128; s > 0; s >>= 1) {
        if (tid < s)
#pragma unroll
            for (int f = 0; f < 16; ++f) red[tid][f] += red[tid + s][f];
        __syncthreads();
    }
    if (tid < 16) {
        int n = hi - lo;
        out[g * 16 + tid] = (n > 0) ? (red[0][tid] / (float)n + b2[tid]) : 0.f;
    }
}

// ----------------------------------------------------------------- launch
extern "C" void kernel_launch(void* const* d_in, const int* in_sizes, int n_in,
                              void* d_out, int out_size, void* d_ws, size_t ws_size,
                              hipStream_t stream) {
    const float* x   = (const float*)d_in[0];
    const float* W1  = (const float*)d_in[1];
    const float* b1  = (const float*)d_in[2];
    const float* W2  = (const float*)d_in[3];
    const float* b2  = (const float*)d_in[4];
    const int*   src = (const int*)d_in[5];
    const int*   dst = (const int*)d_in[6];
    const int*   gid = (const int*)d_in[7];
    float* out = (float*)d_out;

    // workspace layout
    int*   cntO    = (int*)d_ws;                 //    50,176
    int*   cntI    = cntO + 50176;               //    50,176
    int*   rowptr  = cntI + 50176;               //    50,432 (uses 50,001)
    int*   cursor  = rowptr + 50432;             //    50,176
    int*   csr_src = cursor + 50176;             //   800,000
    int*   bsum    = csr_src + 800000;           //       256
    int*   boff    = bsum + 256;                 //       256
    float* rsO     = (float*)(boff + 256);       //    50,176
    float* rsI     = rsO + 50176;                //    50,176
    unsigned short* xs    = (unsigned short*)(rsI + 50176);  // 50,176*128 bf16
    unsigned short* agg1b = xs + (size_t)50176 * 128;        // 50,176*128 bf16 (padded rows)
    unsigned short* w1f   = agg1b + (size_t)50176 * 128;     //    16,384 bf16
    unsigned short* w2f   = w1f + 16384;                     //     2,048 bf16
    float* y    = (float*)(w2f + 2048);          //   800,000 f32
    float* agg2 = y + 800000;                    //   800,000 f32   (~36.3 MB total)

    hipMemsetAsync(d_ws, 0, (size_t)2 * 50176 * sizeof(int), stream);

    k_count<<<(N_EDGES_C + 255) / 256, 256, 0, stream>>>(src, dst, cntO, cntI, N_EDGES_C);
    k_scan1<<<SCAN_NB, 256, 0, stream>>>(cntI, bsum, N_NODES_C);
    k_scan2<<<1, 256, 0, stream>>>(bsum, boff, SCAN_NB);
    k_scan3<<<SCAN_NB, 256, 0, stream>>>(cntI, cntO, boff, rowptr, cursor, rsO, rsI, N_NODES_C);
    k_fill<<<(N_EDGES_C + 255) / 256, 256, 0, stream>>>(src, dst, cursor, csr_src, N_EDGES_C);
    k_wconv<<<9, 256, 0, stream>>>(W1, W2, w1f, w2f);
    k_prep<<<(N_NODES_C * 32 + 255) / 256, 256, 0, stream>>>(x, rsO, xs, N_NODES_C);
    k_agg1b<<<(N_NODES_C * 64 + 255) / 256, 256, 0, stream>>>(xs, rowptr, csr_src, rsI, agg1b, N_NODES_C);
    k_mfma<<<(N_NODES_C + 63) / 64, 256, 0, stream>>>(agg1b, b1, w1f, w2f, rsO, y, N_NODES_C);
    k_agg2<<<(N_NODES_C * 64 + 255) / 256, 256, 0, stream>>>(y, rowptr, csr_src, agg2, N_NODES_C);
    k_pool<<<N_GRAPHS_C, 256, 0, stream>>>(agg2, rsI, gid, b2, out, N_NODES_C);
}

// Round 6
// 132.268 us; speedup vs baseline: 6.4676x; 1.6790x over previous
//
#include <hip/hip_runtime.h>
#include <hip/hip_bf16.h>

#define N_NODES_C 50000
#define N_EDGES_C 800000
#define N_GRAPHS_C 64
#define NBKT 782           // buckets of 64 nodes: (50000+63)>>6
#define BKTP 784           // padded bucket count
#define CHUNK 4096         // edges per histogram/scatter block
#define NBLK_E 196         // 196*4096 = 802816 >= 800000

typedef __attribute__((ext_vector_type(8))) short bf16x8;
typedef __attribute__((ext_vector_type(4))) float f32x4;

__device__ __forceinline__ unsigned short f2bf(float f) {
    unsigned u = __float_as_uint(f);
    unsigned r = (u + 0x7FFFu + ((u >> 16) & 1u)) >> 16;   // RNE
    return (unsigned short)r;
}

// ---------------- pass A: per-block LDS histograms over coarse buckets
__global__ __launch_bounds__(256) void k_hist(
    const int* __restrict__ src, const int* __restrict__ dst,
    int* __restrict__ hmatD, int* __restrict__ hmatS, int nE)
{
    __shared__ int hD[BKTP], hS[BKTP];
    const int tid = threadIdx.x, blk = blockIdx.x;
    for (int i = tid; i < BKTP; i += 256) { hD[i] = 0; hS[i] = 0; }
    __syncthreads();
    const int base = blk * CHUNK;
    for (int i = tid; i < CHUNK; i += 256) {
        int e = base + i;
        if (e < nE) {
            atomicAdd(&hD[dst[e] >> 6], 1);
            atomicAdd(&hS[src[e] >> 6], 1);
        }
    }
    __syncthreads();
    for (int i = tid; i < BKTP; i += 256) {
        hmatD[blk * BKTP + i] = hD[i];
        hmatS[blk * BKTP + i] = hS[i];
    }
}

// ---------------- pass B1: bucket totals (one 64-thr block per bucket, y: D/S)
__global__ __launch_bounds__(64) void k_btot(
    const int* __restrict__ hmatD, const int* __restrict__ hmatS,
    int* __restrict__ btotD, int* __restrict__ btotS)
{
    const int b = blockIdx.x, lane = threadIdx.x;
    const int* hm = blockIdx.y ? hmatS : hmatD;
    int v = 0;
    for (int blk = lane; blk < NBLK_E; blk += 64) v += hm[blk * BKTP + b];
#pragma unroll
    for (int off = 32; off > 0; off >>= 1) v += __shfl_down(v, off, 64);
    if (lane == 0) (blockIdx.y ? btotS : btotD)[b] = v;
}

// ---------------- pass B2: scan bucket totals (1 block per side)
__global__ __launch_bounds__(1024) void k_bscan(
    const int* __restrict__ btotD, const int* __restrict__ btotS,
    int* __restrict__ bbaseD, int* __restrict__ bbaseS)
{
    __shared__ int part[1024];
    const int tid = threadIdx.x;
    const int* bt = blockIdx.x ? btotS : btotD;
    int* bb = blockIdx.x ? bbaseS : bbaseD;
    int v = (tid < NBKT) ? bt[tid] : 0;
    part[tid] = v;
    __syncthreads();
    for (int off = 1; off < 1024; off <<= 1) {
        int t = (tid >= off) ? part[tid - off] : 0;
        __syncthreads();
        part[tid] += t;
        __syncthreads();
    }
    if (tid < NBKT) bb[tid] = part[tid] - v;
    if (tid == NBKT - 1) bb[NBKT] = part[tid];
}

// ---------------- pass B3: per-(bucket,block) scatter offsets
__global__ __launch_bounds__(256) void k_boff(
    const int* __restrict__ hmatD, const int* __restrict__ hmatS,
    const int* __restrict__ bbaseD, const int* __restrict__ bbaseS,
    int* __restrict__ offmatD, int* __restrict__ offmatS)
{
    __shared__ int part[256];
    const int b = blockIdx.x, tid = threadIdx.x;
    const int* hm = blockIdx.y ? hmatS : hmatD;
    const int* bb = blockIdx.y ? bbaseS : bbaseD;
    int* om = blockIdx.y ? offmatS : offmatD;
    int v = (tid < NBLK_E) ? hm[tid * BKTP + b] : 0;
    part[tid] = v;
    __syncthreads();
    for (int off = 1; off < 256; off <<= 1) {
        int t = (tid >= off) ? part[tid - off] : 0;
        __syncthreads();
        part[tid] += t;
        __syncthreads();
    }
    if (tid < NBLK_E) om[tid * BKTP + b] = bb[b] + part[tid] - v;
}

// ---------------- pass C: scatter edges into buckets (LDS cursors only)
__global__ __launch_bounds__(256) void k_scat(
    const int* __restrict__ src, const int* __restrict__ dst,
    const int* __restrict__ offmatD, const int* __restrict__ offmatS,
    unsigned* __restrict__ ed, unsigned char* __restrict__ es, int nE)
{
    __shared__ int curD[BKTP], curS[BKTP];
    const int tid = threadIdx.x, blk = blockIdx.x;
    for (int i = tid; i < BKTP; i += 256) {
        curD[i] = offmatD[blk * BKTP + i];
        curS[i] = offmatS[blk * BKTP + i];
    }
    __syncthreads();
    const int base = blk * CHUNK;
    for (int i = tid; i < CHUNK; i += 256) {
        int e = base + i;
        if (e < nE) {
            unsigned s = (unsigned)src[e], d = (unsigned)dst[e];
            int pD = atomicAdd(&curD[d >> 6], 1);
            ed[pD] = (d << 16) | s;
            int pS = atomicAdd(&curS[s >> 6], 1);
            es[pS] = (unsigned char)(s & 63u);
        }
    }
}

// ---------------- pass D: per-bucket finalize (rowptr/rsI/csr_src | rsO)
__global__ __launch_bounds__(256) void k_bucket(
    const unsigned* __restrict__ ed, const unsigned char* __restrict__ es,
    const int* __restrict__ bbaseD, const int* __restrict__ bbaseS,
    int* __restrict__ rowptr, float* __restrict__ rsI, float* __restrict__ rsO,
    unsigned short* __restrict__ csr_src, int nV)
{
    __shared__ int cnt[64], cur[64];
    const int tid = threadIdx.x;
    const int side = (blockIdx.x >= NBKT);
    const int b = side ? blockIdx.x - NBKT : blockIdx.x;

    if (tid < 64) cnt[tid] = 0;
    __syncthreads();

    if (!side) {
        const int lo = bbaseD[b], hi = bbaseD[b + 1];
        for (int j = lo + tid; j < hi; j += 256)
            atomicAdd(&cnt[(ed[j] >> 16) & 63u], 1);
        __syncthreads();
        if (tid < 64) {
            int c = cnt[tid];
            int v = c;
#pragma unroll
            for (int off = 1; off < 64; off <<= 1) {
                int n = __shfl_up(v, off, 64);
                if (tid >= off) v += n;
            }
            int excl = v - c;
            int node = b * 64 + tid;
            if (node <= nV) rowptr[node] = lo + excl;
            if (node < nV) rsI[node] = rsqrtf((float)max(c, 1));
            cur[tid] = excl;
        }
        __syncthreads();
        for (int j = lo + tid; j < hi; j += 256) {
            unsigned v = ed[j];
            int p = atomicAdd(&cur[(v >> 16) & 63u], 1);
            csr_src[lo + p] = (unsigned short)(v & 0xFFFFu);
        }
    } else {
        const int lo = bbaseS[b], hi = bbaseS[b + 1];
        for (int j = lo + tid; j < hi; j += 256)
            atomicAdd(&cnt[es[j]], 1);
        __syncthreads();
        if (tid < 64) {
            int node = b * 64 + tid;
            if (node < nV) rsO[node] = rsqrtf((float)max(cnt[tid], 1));
        }
    }
}

// --------------------------------------------- xs = bf16(x * rsO), 256 B rows
__global__ __launch_bounds__(256) void k_prep(
    const float* __restrict__ x, const float* __restrict__ rsO,
    unsigned short* __restrict__ xs, int nV)
{
    int t = blockIdx.x * 256 + threadIdx.x;
    if (t >= nV * 32) return;
    int v = t >> 5, q = t & 31;
    float w = rsO[v];
    float4 a = ((const float4*)(x + (size_t)v * 128))[q];
    ushort4 o;
    o.x = f2bf(a.x * w); o.y = f2bf(a.y * w);
    o.z = f2bf(a.z * w); o.w = f2bf(a.w * w);
    ((ushort4*)(xs + (size_t)v * 128))[q] = o;
}

// ------------- W1/W2 -> bf16 fragment order for mfma_f32_16x16x32_bf16 B-frags
__global__ __launch_bounds__(256) void k_wconv(
    const float* __restrict__ W1, const float* __restrict__ W2,
    unsigned short* __restrict__ w1f, unsigned short* __restrict__ w2f)
{
    int t = blockIdx.x * 256 + threadIdx.x;
    if (t < 2048) {
        int kk = t >> 9, nt = (t >> 6) & 7, l = t & 63;
        int kb = kk * 32 + ((l >> 4) << 3), n = nt * 16 + (l & 15);
        ushort4 lo, hi;
        lo.x = f2bf(W1[(kb + 0) * 128 + n]); lo.y = f2bf(W1[(kb + 1) * 128 + n]);
        lo.z = f2bf(W1[(kb + 2) * 128 + n]); lo.w = f2bf(W1[(kb + 3) * 128 + n]);
        hi.x = f2bf(W1[(kb + 4) * 128 + n]); hi.y = f2bf(W1[(kb + 5) * 128 + n]);
        hi.z = f2bf(W1[(kb + 6) * 128 + n]); hi.w = f2bf(W1[(kb + 7) * 128 + n]);
        ((ushort4*)(w1f + t * 8))[0] = lo;
        ((ushort4*)(w1f + t * 8))[1] = hi;
    } else if (t < 2304) {
        int t2 = t - 2048;
        int kk = t2 >> 6, l = t2 & 63;
        int kb = kk * 32 + ((l >> 4) << 3), n = l & 15;
        ushort4 lo, hi;
        lo.x = f2bf(W2[(kb + 0) * 16 + n]); lo.y = f2bf(W2[(kb + 1) * 16 + n]);
        lo.z = f2bf(W2[(kb + 2) * 16 + n]); lo.w = f2bf(W2[(kb + 3) * 16 + n]);
        hi.x = f2bf(W2[(kb + 4) * 16 + n]); hi.y = f2bf(W2[(kb + 5) * 16 + n]);
        hi.z = f2bf(W2[(kb + 6) * 16 + n]); hi.w = f2bf(W2[(kb + 7) * 16 + n]);
        ((ushort4*)(w2f + t2 * 8))[0] = lo;
        ((ushort4*)(w2f + t2 * 8))[1] = hi;
    }
}

// ---------------- layer-1 aggregation (bf16 gather, 4 edges per wave-load)
__global__ __launch_bounds__(256) void k_agg1b(
    const unsigned short* __restrict__ xs, const int* __restrict__ rowptr,
    const unsigned short* __restrict__ csr_src, const float* __restrict__ rsI,
    unsigned short* __restrict__ agg1b, int nV)
{
    long long t = (long long)blockIdx.x * blockDim.x + threadIdx.x;
    int v = (int)(t >> 6);
    int lane = (int)(t & 63);
    if (v >= nV) return;
    int g = lane >> 4, fl = lane & 15;
    int beg = rowptr[v], end = rowptr[v + 1];
    float acc[8];
#pragma unroll
    for (int k = 0; k < 8; ++k) acc[k] = 0.f;

    for (int j = beg + g; j < end; j += 4) {
        int s = csr_src[j];
        uint4 w = *(const uint4*)(xs + (size_t)s * 128 + fl * 8);
        acc[0] += __uint_as_float(w.x << 16);
        acc[1] += __uint_as_float(w.x & 0xFFFF0000u);
        acc[2] += __uint_as_float(w.y << 16);
        acc[3] += __uint_as_float(w.y & 0xFFFF0000u);
        acc[4] += __uint_as_float(w.z << 16);
        acc[5] += __uint_as_float(w.z & 0xFFFF0000u);
        acc[6] += __uint_as_float(w.w << 16);
        acc[7] += __uint_as_float(w.w & 0xFFFF0000u);
    }
#pragma unroll
    for (int k = 0; k < 8; ++k) {
        acc[k] += __shfl_xor(acc[k], 16, 64);
        acc[k] += __shfl_xor(acc[k], 32, 64);
    }
    float ri = rsI[v];
    if (g < 2) {
        ushort4 o;
        o.x = f2bf(acc[g * 4 + 0] * ri);
        o.y = f2bf(acc[g * 4 + 1] * ri);
        o.z = f2bf(acc[g * 4 + 2] * ri);
        o.w = f2bf(acc[g * 4 + 3] * ri);
        *(ushort4*)(agg1b + (size_t)v * 128 + fl * 8 + g * 4) = o;
    }
}

// -------------------- fused MFMA GEMMs: h1 = relu(agg1b@W1+b1); y = (h1@W2)*rsO
__global__ __launch_bounds__(256) void k_mfma(
    const unsigned short* __restrict__ agg1b, const float* __restrict__ b1,
    const unsigned short* __restrict__ w1f, const unsigned short* __restrict__ w2f,
    const float* __restrict__ rsO, unsigned short* __restrict__ y, int nV)
{
    __shared__ __align__(16) unsigned short h1[64 * 136];
    const int tid = threadIdx.x;
    const int w = tid >> 6, l = tid & 63;
    const int lr = l & 15, lg = l >> 4;
    const int row0 = blockIdx.x * 64;

    bf16x8 a[4];
    const unsigned short* abase = agg1b + (size_t)(row0 + w * 16 + lr) * 128 + lg * 8;
#pragma unroll
    for (int kk = 0; kk < 4; ++kk)
        a[kk] = *(const bf16x8*)(abase + kk * 32);

    f32x4 acc[8];
#pragma unroll
    for (int nt = 0; nt < 8; ++nt) acc[nt] = (f32x4){0.f, 0.f, 0.f, 0.f};

#pragma unroll
    for (int nt = 0; nt < 8; ++nt)
#pragma unroll
        for (int kk = 0; kk < 4; ++kk) {
            bf16x8 b = *(const bf16x8*)(w1f + ((kk * 8 + nt) * 64 + l) * 8);
            acc[nt] = __builtin_amdgcn_mfma_f32_16x16x32_bf16(a[kk], b, acc[nt], 0, 0, 0);
        }

#pragma unroll
    for (int nt = 0; nt < 8; ++nt) {
        float bb = b1[nt * 16 + lr];
#pragma unroll
        for (int i = 0; i < 4; ++i) {
            float h = fmaxf(acc[nt][i] + bb, 0.f);
            h1[(w * 16 + lg * 4 + i) * 136 + nt * 16 + lr] = f2bf(h);
        }
    }
    __syncthreads();

    f32x4 acc2 = (f32x4){0.f, 0.f, 0.f, 0.f};
#pragma unroll
    for (int kk = 0; kk < 4; ++kk) {
        bf16x8 a2 = *(const bf16x8*)(&h1[(w * 16 + lr) * 136 + kk * 32 + lg * 8]);
        bf16x8 b2 = *(const bf16x8*)(w2f + (kk * 64 + l) * 8);
        acc2 = __builtin_amdgcn_mfma_f32_16x16x32_bf16(a2, b2, acc2, 0, 0, 0);
    }
#pragma unroll
    for (int i = 0; i < 4; ++i) {
        int r = row0 + w * 16 + lg * 4 + i;
        if (r < nV) y[(size_t)r * 16 + lr] = f2bf(acc2[i] * rsO[r]);
    }
}

// ------------------------------------- layer-2 aggregation (bf16 y gather)
__global__ __launch_bounds__(256) void k_agg2(
    const unsigned short* __restrict__ y, const int* __restrict__ rowptr,
    const unsigned short* __restrict__ csr_src, float* __restrict__ agg2, int nV)
{
    long long t = (long long)blockIdx.x * blockDim.x + threadIdx.x;
    int v = (int)(t >> 6);
    int lane = (int)(t & 63);
    if (v >= nV) return;
    int f = lane & 15, g = lane >> 4;
    int beg = rowptr[v], end = rowptr[v + 1];
    float acc = 0.f;
    for (int j = beg + g; j < end; j += 4) {
        int s = csr_src[j];
        unsigned u = y[(size_t)s * 16 + f];
        acc += __uint_as_float(u << 16);
    }
    acc += __shfl_xor(acc, 16, 64);
    acc += __shfl_xor(acc, 32, 64);
    if (g == 0) agg2[(size_t)v * 16 + f] = acc;
}

// ------------------------------------------------- per-graph mean pool (+b2)
__device__ __forceinline__ int lowerb(const int* __restrict__ a, int n, int key) {
    int lo = 0, hi = n;
    while (lo < hi) { int m = (lo + hi) >> 1; if (a[m] < key) lo = m + 1; else hi = m; }
    return lo;
}

__global__ __launch_bounds__(256) void k_pool(
    const float* __restrict__ agg2, const float* __restrict__ rsI,
    const int* __restrict__ gid, const float* __restrict__ b2,
    float* __restrict__ out, int nV)
{
    __shared__ float red[256][16];
    const int g = blockIdx.x;
    const int tid = threadIdx.x;
    const int lo = lowerb(gid, nV, g);
    const int hi = lowerb(gid, nV, g + 1);

    float acc[16];
#pragma unroll
    for (int f = 0; f < 16; ++f) acc[f] = 0.f;

    for (int v = lo + tid; v < hi; v += 256) {
        float w = rsI[v];
        const float4* p = (const float4*)(agg2 + (size_t)v * 16);
        float4 a = p[0], b = p[1], c = p[2], d = p[3];
        acc[0] += a.x * w; acc[1] += a.y * w; acc[2]  += a.z * w; acc[3]  += a.w * w;
        acc[4] += b.x * w; acc[5] += b.y * w; acc[6]  += b.z * w; acc[7]  += b.w * w;
        acc[8] += c.x * w; acc[9] += c.y * w; acc[10] += c.z * w; acc[11] += c.w * w;
        acc[12] += d.x * w; acc[13] += d.y * w; acc[14] += d.z * w; acc[15] += d.w * w;
    }
#pragma unroll
    for (int f = 0; f < 16; ++f) red[tid][f] = acc[f];
    __syncthreads();
    for (int s = 128; s > 0; s >>= 1) {
        if (tid < s)
#pragma unroll
            for (int f = 0; f < 16; ++f) red[tid][f] += red[tid + s][f];
        __syncthreads();
    }
    if (tid < 16) {
        int n = hi - lo;
        out[g * 16 + tid] = (n > 0) ? (red[0][tid] / (float)n + b2[tid]) : 0.f;
    }
}

// ----------------------------------------------------------------- launch
extern "C" void kernel_launch(void* const* d_in, const int* in_sizes, int n_in,
                              void* d_out, int out_size, void* d_ws, size_t ws_size,
                              hipStream_t stream) {
    const float* x   = (const float*)d_in[0];
    const float* W1  = (const float*)d_in[1];
    const float* b1  = (const float*)d_in[2];
    const float* W2  = (const float*)d_in[3];
    const float* b2  = (const float*)d_in[4];
    const int*   src = (const int*)d_in[5];
    const int*   dst = (const int*)d_in[6];
    const int*   gid = (const int*)d_in[7];
    float* out = (float*)d_out;

    // ---- workspace layout (int elements) -------------------------------
    int* p = (int*)d_ws;
    int*   btotD   = p;            p += 784;
    int*   btotS   = p;            p += 784;
    int*   bbaseD  = p;            p += 800;     // uses NBKT+1 = 783
    int*   bbaseS  = p;            p += 800;
    int*   rowptr  = p;            p += 50432;   // uses 50001
    float* rsO     = (float*)p;    p += 50176;
    float* rsI     = (float*)p;    p += 50176;
    unsigned short* csr_src = (unsigned short*)p; p += 400128;  // 800k ushort
    unsigned short* w1f = (unsigned short*)p;     p += 8192;    // 16384 bf16
    unsigned short* w2f = (unsigned short*)p;     p += 1024;    // 2048 bf16
    unsigned short* y   = (unsigned short*)p;     p += 401408;  // 50176*16 bf16
    float* agg2    = (float*)p;    p += 800000;
    int*   BIG     = p;            // 6,422,528 ints (xs+agg1b), aliased below
    // build-phase aliases inside BIG (dead before xs/agg1b are written):
    int*   hmatD   = BIG;                        // 196*784 = 153,664
    int*   hmatS   = BIG + 153664;               // 153,664
    int*   offmatD = BIG + 307328;               // 153,664
    int*   offmatS = BIG + 460992;               // 153,664
    unsigned*      ed = (unsigned*)(BIG + 614656);        // 800,000 uint
    unsigned char* es = (unsigned char*)(BIG + 1414656);  // 800,000 B
    // compute-phase views of BIG:
    unsigned short* xs    = (unsigned short*)BIG;            // 50176*128 bf16
    unsigned short* agg1b = (unsigned short*)(BIG + 3211264);// 50176*128 bf16

    // ---- CSR build: two-level counting sort, zero global atomics -------
    k_hist <<<NBLK_E, 256, 0, stream>>>(src, dst, hmatD, hmatS, N_EDGES_C);
    k_btot <<<dim3(NBKT, 2), 64, 0, stream>>>(hmatD, hmatS, btotD, btotS);
    k_bscan<<<2, 1024, 0, stream>>>(btotD, btotS, bbaseD, bbaseS);
    k_boff <<<dim3(NBKT, 2), 256, 0, stream>>>(hmatD, hmatS, bbaseD, bbaseS, offmatD, offmatS);
    k_scat <<<NBLK_E, 256, 0, stream>>>(src, dst, offmatD, offmatS, ed, es, N_EDGES_C);
    k_bucket<<<2 * NBKT, 256, 0, stream>>>(ed, es, bbaseD, bbaseS, rowptr, rsI, rsO, csr_src, N_NODES_C);

    // ---- compute pipeline ---------------------------------------------
    k_wconv<<<9, 256, 0, stream>>>(W1, W2, w1f, w2f);
    k_prep <<<(N_NODES_C * 32 + 255) / 256, 256, 0, stream>>>(x, rsO, xs, N_NODES_C);
    k_agg1b<<<(N_NODES_C * 64 + 255) / 256, 256, 0, stream>>>(xs, rowptr, csr_src, rsI, agg1b, N_NODES_C);
    k_mfma <<<(N_NODES_C + 63) / 64, 256, 0, stream>>>(agg1b, b1, w1f, w2f, rsO, y, N_NODES_C);
    k_agg2 <<<(N_NODES_C * 64 + 255) / 256, 256, 0, stream>>>(y, rowptr, csr_src, agg2, N_NODES_C);
    k_pool <<<N_GRAPHS_C, 256, 0, stream>>>(agg2, rsI, gid, b2, out, N_NODES_C);
}